// Round 5
// baseline (326.416 us; speedup 1.0000x reference)
//
#include <hip/hip_runtime.h>

#define T_STEPS 1024
#define B_DIM   128
#define D_DIM   256
#define H_DIM   256
#define DH      512   // D + H
#define INV2PI  0.15915494309189535f

// tanh(x) Pade(5,4): x(x^4+105x^2+945)/(15x^4+420x^2+945); err<1e-4 for |x|<=2.3.
// |c| provably <= 2.08 (fixed point of f*c+i*g with f,i<=0.731, g<=0.762).
__device__ __forceinline__ float tanh_pade(float x) {
    float t = x * x;
    float n = fmaf(t, t + 105.0f, 945.0f);
    float d = fmaf(t, fmaf(t, 15.0f, 420.0f), 945.0f);
    return x * n * __builtin_amdgcn_rcpf(d);
}

// quad_perm broadcast of role K within each 4-lane group (VALU DPP, no LDS).
template <int K>
__device__ __forceinline__ float quad_bcast(float v) {
    int r = __builtin_amdgcn_mov_dpp(__builtin_bit_cast(int, v), K * 0x55, 0xF, 0xF, true);
    return __builtin_bit_cast(float, r);
}

// xdot[row][k] = (x[row,:] . W[k,:256] + b[k]) * 1/(2*pi)  — pre-scaled to
// revolutions so k_scan can feed v_sin_f32 directly. Wave per row, grid-stride.
// Transpose-reduce: 7 shuffles/row instead of 24 (4 independent butterflies).
__global__ __launch_bounds__(256) void k_xdot(const float* __restrict__ x,
                                              const float* __restrict__ W,
                                              const float* __restrict__ bias,
                                              float* __restrict__ xdot) {
    const int lane = threadIdx.x & 63;
    const int wid = blockIdx.x * (blockDim.x >> 6) + (threadIdx.x >> 6);
    const int nw = (gridDim.x * blockDim.x) >> 6;
    const int nrows = T_STEPS * B_DIM;

    float4 wk0 = ((const float4*)(W + 0 * DH))[lane];
    float4 wk1 = ((const float4*)(W + 1 * DH))[lane];
    float4 wk2 = ((const float4*)(W + 2 * DH))[lane];
    float4 wk3 = ((const float4*)(W + 3 * DH))[lane];
    const float bl = bias[lane & 3];   // bias for the gate this lane will own

    const float4* xv4 = (const float4*)x;  // 64 float4 per row

    const bool b0 = (lane & 1) != 0;
    const bool b1 = (lane & 2) != 0;

    int row = wid;
    if (row >= nrows) return;
    float4 xv = xv4[row * 64 + lane];
    for (; row < nrows; row += nw) {
        float4 cur = xv;
        int nrow = row + nw;
        if (nrow < nrows) xv = xv4[nrow * 64 + lane];  // prefetch next row

        float p0 = fmaf(cur.x, wk0.x, fmaf(cur.y, wk0.y, fmaf(cur.z, wk0.z, cur.w * wk0.w)));
        float p1 = fmaf(cur.x, wk1.x, fmaf(cur.y, wk1.y, fmaf(cur.z, wk1.z, cur.w * wk1.w)));
        float p2 = fmaf(cur.x, wk2.x, fmaf(cur.y, wk2.y, fmaf(cur.z, wk2.z, cur.w * wk2.w)));
        float p3 = fmaf(cur.x, wk3.x, fmaf(cur.y, wk3.y, fmaf(cur.z, wk3.z, cur.w * wk3.w)));

        // stage 1: exchange across xor 1
        float sA = b0 ? p0 : p1;
        sA = __shfl_xor(sA, 1, 64);
        float A = (b0 ? p1 : p0) + sA;      // pair-sum of p_{bit0}
        float sB = b0 ? p2 : p3;
        sB = __shfl_xor(sB, 1, 64);
        float B = (b0 ? p3 : p2) + sB;      // pair-sum of p_{2+bit0}
        // stage 2: exchange across xor 2
        float s2 = b1 ? A : B;
        s2 = __shfl_xor(s2, 2, 64);
        float v = (b1 ? B : A) + s2;        // 4-lane-group sum of p_{lane&3}
        // stage 3: butterfly over the 16 groups
#pragma unroll
        for (int off = 4; off < 64; off <<= 1) v += __shfl_xor(v, off, 64);

        if (lane < 4) xdot[row * 4 + lane] = (v + bl) * INV2PI;
    }
}

// Sequential scan, 4 LANES PER CHAIN, LDS double-buffered input staging.
// 512 threads = 2 blocks x 256 (1 wave/SIMD on 2 CUs). Lane r = tid&3 owns
// gate r of chain tid>>2 (f/i/g/o); gates exchanged via DPP quad_perm.
// Staging (T14 async-split): per 16-step tile — ds_read current tile to regs,
// ISSUE next tile's 16 coalesced global loads to regs, compute 16 steps
// (~1400 cy, hides the ~300-500 cy L2 latency), ds_write the fetched tile to
// the other LDS buffer, one barrier. Unlike the register-ring versions
// (r1-r4), the barrier+LDS dataflow makes load-sinking structurally bounded:
// worst case exposes one latency per TILE, not per step.
__global__ __launch_bounds__(256)
__attribute__((amdgpu_waves_per_eu(1, 1)))
void k_scan(const float* __restrict__ xdot,
            const float* __restrict__ W,
            float* __restrict__ hseq,
            float* __restrict__ cfin) {
    const int ltid = threadIdx.x;                       // 0..255
    const int gtid = blockIdx.x * 256 + ltid;           // 0..511
    const int r = gtid & 3;                             // gate role
    const int chain = gtid >> 2;                        // 0..127
    const int gbase = blockIdx.x * 256;

    __shared__ float s_whp[4];
    __shared__ float tile[2][16][256];                  // 32 KB

    {   // whp[k] = sum_h W[k, 256+h]; groups of 32 threads per k (redundant ok)
        int k = (ltid >> 5) & 3, j = ltid & 31;
        const float4* wr = (const float4*)(W + k * DH + D_DIM + j * 8);
        float4 v0 = wr[0], v1 = wr[1];
        float s = (v0.x + v0.y) + (v0.z + v0.w) + (v1.x + v1.y) + (v1.z + v1.w);
#pragma unroll
        for (int off = 16; off > 0; off >>= 1) s += __shfl_xor(s, off, 32);
        if (j == 0) s_whp[k] = s;
    }

    // prologue: stage tile 0
#pragma unroll
    for (int k = 0; k < 16; ++k)
        tile[0][k][ltid] = xdot[k * 512 + gbase + ltid];
    __syncthreads();

    const float wl = s_whp[r] * INV2PI;   // REVOLUTIONS: matches xdot scaling

    const bool isg = (r == 2);
    const float B0 = isg ? 0.0f       : 0.5f;
    const float B1 = isg ? 0.999904f  : 0.25f;
    const float B3 = isg ? -0.331065f : -1.0f / 48.0f;
    const float B5 = isg ? 0.120472f  : 1.0f / 480.0f;
    const float B7 = isg ? -0.027717f : -17.0f / 80640.0f;

    float c = 0.0f, h = 0.0f;
    float4 h4;
    float4* hout4 = (float4*)(hseq + chain * T_STEPS);  // [b][t] layout

    for (int T = 0; T < T_STEPS / 16; ++T) {
        const int cur = T & 1;

        // current tile LDS -> regs (conflict-free: lanes consecutive)
        float v[16];
#pragma unroll
        for (int k = 0; k < 16; ++k) v[k] = tile[cur][k][ltid];

        // issue next tile's global loads (coalesced; results used after compute)
        float g16[16];
        const bool more = (T < T_STEPS / 16 - 1);
        if (more) {
#pragma unroll
            for (int k = 0; k < 16; ++k)
                g16[k] = xdot[((T + 1) * 16 + k) * 512 + gbase + ltid];
        }

        // compute 16 steps — pure VALU/trans, no memory on critical path
#pragma unroll
        for (int j = 0; j < 16; ++j) {
            float sn = __builtin_amdgcn_sinf(fmaf(h, wl, v[j]));  // q_r
            float t = sn * sn;
            float p = fmaf(t, B7, B5);
            p = fmaf(t, p, B3);
            p = fmaf(t, p, B1);
            float gate = fmaf(sn, p, B0);       // f/i/o: sigmoid(q); g: tanh(q)

            float fv = quad_bcast<0>(gate);
            float iv = quad_bcast<1>(gate);
            float gv = quad_bcast<2>(gate);
            float ov = quad_bcast<3>(gate);

            c = fmaf(fv, c, iv * gv);
            h = ov * tanh_pade(c);              // uniform across the quad

            if ((j & 3) == 0)      h4.x = h;
            else if ((j & 3) == 1) h4.y = h;
            else if ((j & 3) == 2) h4.z = h;
            else { h4.w = h; if (r == 0) hout4[(T * 16 + j) >> 2] = h4; }
        }

        // write-late: park fetched tile in the other LDS buffer
        if (more) {
#pragma unroll
            for (int k = 0; k < 16; ++k) tile[cur ^ 1][k][ltid] = g16[k];
        }
        __syncthreads();
    }
    if (r == 0) cfin[chain] = c;
}

// broadcast h over H=256 columns; wave per output row of 64 float4s.
// rows: [0,131072) stacked, [131072,131200) hx, [131200,131328) cx
// hseq is [b][t]-major: value for output row r=(t*128+b) is hseq[b*1024 + t].
__global__ __launch_bounds__(256) void k_bcast(const float* __restrict__ hseq,
                                               const float* __restrict__ cfin,
                                               float4* __restrict__ out) {
    const int wave = blockIdx.x * (blockDim.x >> 6) + (threadIdx.x >> 6);
    const int lane = threadIdx.x & 63;
    const int NR = T_STEPS * B_DIM;
    if (wave >= NR + 2 * B_DIM) return;
    float v;
    if (wave < NR) {
        int t = wave >> 7, bb = wave & 127;
        v = hseq[bb * T_STEPS + t];
    } else if (wave < NR + B_DIM) {
        v = hseq[(wave - NR) * T_STEPS + (T_STEPS - 1)];
    } else {
        v = cfin[wave - NR - B_DIM];
    }
    out[(size_t)wave * 64 + lane] = make_float4(v, v, v, v);
}

extern "C" void kernel_launch(void* const* d_in, const int* in_sizes, int n_in,
                              void* d_out, int out_size, void* d_ws, size_t ws_size,
                              hipStream_t stream) {
    const float* x = (const float*)d_in[0];   // (1024,128,256) f32
    const float* W = (const float*)d_in[1];   // (4,512) f32
    const float* b = (const float*)d_in[2];   // (4,) f32
    // d_in[3] = qw — mathematically inert (sin invariant under RX then H)

    float* out = (float*)d_out;

    float* wsf  = (float*)d_ws;
    float* hseq = wsf + 16;                      // 131072 floats, [b][t]
    float* cfin = wsf + 16 + T_STEPS * B_DIM;    // 128 floats
    float* xdot = out;  // 2 MB scratch in d_out head; d_out is fully
                        // overwritten by k_bcast afterwards.

    k_xdot<<<2048, 256, 0, stream>>>(x, W, b, xdot);
    k_scan<<<2, 256, 0, stream>>>(xdot, W, hseq, cfin);

    const int rows = T_STEPS * B_DIM + 2 * B_DIM;          // 131328
    k_bcast<<<(rows + 3) / 4, 256, 0, stream>>>(hseq, cfin, (float4*)out);
}